// Round 2
// baseline (324.504 us; speedup 1.0000x reference)
//
#include <hip/hip_runtime.h>
#include <cstdint>
#include <cstddef>

// ---------- types ----------
typedef __attribute__((ext_vector_type(8))) __bf16 bf16x8;
typedef __attribute__((ext_vector_type(4))) float floatx4;

__device__ __forceinline__ unsigned short f2bf(float f) {
    unsigned int u = __float_as_uint(f);
    u += 0x7fffu + ((u >> 16) & 1u);      // RNE
    return (unsigned short)(u >> 16);
}

__device__ __forceinline__ void async_copy16(const void* gp, void* lp) {
    __builtin_amdgcn_global_load_lds(
        (__attribute__((address_space(1))) void*)gp,
        (__attribute__((address_space(3))) void*)lp,
        16, 0, 0);
}

// ---------- constants ----------
#define CCH 512
#define AREA 4096
#define NGRP 32
#define TB (AREA * CCH)        // per-batch tensor elements (2097152)

// =====================================================================
// S+exp, 256x256 tile, 8-wave, 8-phase schedule with counted vmcnt.
// A = K-vectors [4096][1024(ld)] bf16 (+512 col offset applied by host)
// B = Q-vectors [4096][1024] bf16
// P[b][i][j] = fp8(exp2(acc*ec1 + mec2)); lsum[b][i] += row sums.
//   i (P row) = n from B (Q); j (P col) = m from A (K).
// K = 512 -> 8 K-tiles of BK=64. Double-buffered LDS (128 KB):
//   As[2][256][64]bf16 at 0/32K, Bs[2][256][64] at 64K/96K.
// Staging granularity: quarter-tile = 64 rows x 128 B = 1 load/thread.
// Stream (per tile tau): [Ae0 Ae2 | Bq0 Bq1 | Bq2 Bq3 | Ao1 Ao3]
//   staged at group tau-2 ph2/ph3/ph4 and group tau-1 ph1.
// Boundary wait: vmcnt(6) (3 quarter-pairs of tile t+2 stay in flight);
//   vmcnt(0) only entering the last group. Raw s_barrier everywhere.
// Hazard proof: every quarter staged into the LIVE buffer (tile t+2,
//   phases 2-4) covers rows whose ds_reads completed at a strictly
//   earlier phase (Ae read ph1 -> staged ph2; B read ph1+2 -> staged
//   ph3/4). Inter-phase barriers order issue; vmcnt orders data.
// =====================================================================
#define SBAR do { __builtin_amdgcn_sched_barrier(0);          \
                  __builtin_amdgcn_s_barrier();               \
                  __builtin_amdgcn_sched_barrier(0); } while (0)

#define LOAD_AF(MH)                                                       \
    _Pragma("unroll")                                                     \
    for (int i = 0; i < 4; ++i)                                           \
        _Pragma("unroll")                                                 \
        for (int ks = 0; ks < 2; ++ks)                                    \
            af[i * 2 + ks] = *(const bf16x8*)(Ab_ +                       \
                ((aBase + (MH) * 8192 + i * 2048) ^ (ks << 6)));

#define LOAD_BG(NH, BG)                                                   \
    _Pragma("unroll")                                                     \
    for (int j = 0; j < 2; ++j)                                           \
        _Pragma("unroll")                                                 \
        for (int ks = 0; ks < 2; ++ks)                                    \
            BG[j * 2 + ks] = *(const bf16x8*)(Bb_ +                       \
                ((bBase + (NH) * 4096 + j * 2048) ^ (ks << 6)));

#define MFMA_QUAD(MH, NH, BG)                                             \
    __builtin_amdgcn_s_setprio(1);                                       \
    _Pragma("unroll")                                                     \
    for (int ks = 0; ks < 2; ++ks)                                        \
        _Pragma("unroll")                                                 \
        for (int i = 0; i < 4; ++i)                                       \
            _Pragma("unroll")                                             \
            for (int j = 0; j < 2; ++j)                                   \
                acc[(MH) * 4 + i][(NH) * 2 + j] =                         \
                    __builtin_amdgcn_mfma_f32_16x16x32_bf16(              \
                        af[i * 2 + ks], BG[j * 2 + ks],                   \
                        acc[(MH) * 4 + i][(NH) * 2 + j], 0, 0, 0);        \
    __builtin_amdgcn_s_setprio(0);

#define STAGE_A(T, Q) async_copy16(Apb + (size_t)(T) * 128 + qOff[Q],     \
    smemb + (((T) & 1) * 32768 + (Q) * 8192) + tid * 16)
#define STAGE_B(T, Q) async_copy16(Bpb + (size_t)(T) * 128 + qOff[Q],     \
    smemb + (65536 + ((T) & 1) * 32768 + (Q) * 8192) + tid * 16)

__global__ __launch_bounds__(512, 1) void s_exp8(
    const unsigned short* __restrict__ A, const unsigned short* __restrict__ B,
    unsigned char* __restrict__ P, float* __restrict__ lsum)
{
    __shared__ __align__(16) unsigned char smem[131072];
    char* smemb = (char*)smem;

    const int tid  = threadIdx.x;
    const int w    = tid >> 6;
    const int lane = tid & 63;
    const int lr = lane & 15;
    const int lq = lane >> 4;
    const int sw = lr & 7;
    const int wm = (w >> 2) * 128;       // col (m, from A) half
    const int wn = (w & 3) * 64;         // row (n, from B) quarter

    const int m0 = blockIdx.y * 256;
    const int n0 = blockIdx.x * 256;
    const int bz = blockIdx.z;

    const char* Apb = (const char*)(A + (size_t)bz * (AREA * 1024) + (size_t)m0 * 1024);
    const char* Bpb = (const char*)(B + (size_t)bz * (AREA * 1024) + (size_t)n0 * 1024);

    // per-thread staging byte offset per quarter (lda == ldb == 1024 elems)
    unsigned int qOff[4];
#pragma unroll
    for (int q = 0; q < 4; ++q) {
        int row = q * 64 + (tid >> 3);
        int scc = (tid & 7) ^ (row & 7);
        qOff[q] = (unsigned int)(row * 1024 + (scc << 3)) * 2u;
    }
    const int aBase = (wm + lr) * 128 + ((lq ^ sw) << 4);
    const int bBase = (wn + lr) * 128 + ((lq ^ sw) << 4);

    floatx4 acc[8][4];
#pragma unroll
    for (int i = 0; i < 8; ++i)
#pragma unroll
        for (int j = 0; j < 4; ++j) acc[i][j] = floatx4{0.f, 0.f, 0.f, 0.f};

    bf16x8 af[8], bg0[4], bg1[4];

    // ---- prologue: tile0 (8 quarters) + tile1 first 6 quarters ----
    STAGE_A(0, 0); STAGE_A(0, 1); STAGE_A(0, 2); STAGE_A(0, 3);
    STAGE_B(0, 0); STAGE_B(0, 1); STAGE_B(0, 2); STAGE_B(0, 3);
    STAGE_A(1, 0); STAGE_A(1, 2);
    STAGE_B(1, 0); STAGE_B(1, 1); STAGE_B(1, 2); STAGE_B(1, 3);
    asm volatile("s_waitcnt vmcnt(6)" ::: "memory");
    SBAR;

    for (int t = 0; t < 8; ++t) {
        const char* Ab_ = smemb + (t & 1) * 32768;
        const char* Bb_ = smemb + 65536 + (t & 1) * 32768;

        // ---------- phase 1: af[mh0] + bg0; stage Ao pair of t+1 ----------
        LOAD_AF(0);
        LOAD_BG(0, bg0);
        if (t < 7) { STAGE_A(t + 1, 1); STAGE_A(t + 1, 3); }
        SBAR;
        MFMA_QUAD(0, 0, bg0);
        SBAR;

        // ---------- phase 2: bg1; stage Ae pair of t+2 ----------
        LOAD_BG(1, bg1);
        if (t < 6) { STAGE_A(t + 2, 0); STAGE_A(t + 2, 2); }
        SBAR;
        MFMA_QUAD(0, 1, bg1);
        SBAR;

        // ---------- phase 3: af[mh1]; stage B q0,q1 of t+2 ----------
        LOAD_AF(1);
        if (t < 6) { STAGE_B(t + 2, 0); STAGE_B(t + 2, 1); }
        SBAR;
        MFMA_QUAD(1, 1, bg1);
        SBAR;

        // ---------- phase 4: no reads; stage B q2,q3 of t+2 ----------
        if (t < 6) { STAGE_B(t + 2, 2); STAGE_B(t + 2, 3); }
        SBAR;
        MFMA_QUAD(1, 0, bg0);
        if (t < 6)      asm volatile("s_waitcnt vmcnt(6)" ::: "memory");
        else if (t == 6) asm volatile("s_waitcnt vmcnt(0)" ::: "memory");
        SBAR;
    }

    // ---- epilogue: exp2 + fp8 pack via Ct bounce (aliases smem) ----
    unsigned char* Ct = (unsigned char*)smem;   // 256 x 272 = 69632 B
    const float ec1  = 0.044194173824159216f * 1.44269504f;
    const float mec2 = -5.77078016f;
    float* ls = lsum + (size_t)bz * AREA + n0;
#pragma unroll
    for (int jn = 0; jn < 4; ++jn) {
        const int nl = wn + jn * 16 + lr;
        float rs = 0.f;
#pragma unroll
        for (int im = 0; im < 8; ++im) {
            float e0 = exp2f(fmaf(acc[im][jn][0], ec1, mec2));
            float e1 = exp2f(fmaf(acc[im][jn][1], ec1, mec2));
            float e2 = exp2f(fmaf(acc[im][jn][2], ec1, mec2));
            float e3 = exp2f(fmaf(acc[im][jn][3], ec1, mec2));
            rs += (e0 + e1) + (e2 + e3);
            int pk = __builtin_amdgcn_cvt_pk_fp8_f32(e0, e1, 0, false);
            pk = __builtin_amdgcn_cvt_pk_fp8_f32(e2, e3, pk, true);
            *(unsigned int*)&Ct[nl * 272 + wm + im * 16 + lq * 4] =
                (unsigned int)pk;
        }
        rs += __shfl_xor(rs, 16);
        rs += __shfl_xor(rs, 32);
        if (lq == 0) atomicAdd(&ls[nl], rs);
    }
    __syncthreads();
    const int row  = tid >> 1;
    const int half = (tid & 1) * 128;
    unsigned char* dstp = P + (size_t)bz * ((size_t)AREA * AREA) +
                          (size_t)(n0 + row) * AREA + m0 + half;
    const unsigned char* srcp = &Ct[row * 272 + half];
#pragma unroll
    for (int k2 = 0; k2 < 8; ++k2)
        *(uint4*)(dstp + k2 * 16) = *(const uint4*)(srcp + k2 * 16);
}

// =====================================================================
// TN GEMM (bf16 inputs): C[m][n] = alpha * sum_k A[m][k]*B[n][k]
// BIAS_MODE: 0 none, 1 per-m, 2 per-n.  (2-phase 128^2 structure)
// =====================================================================
template<int TBM, int TBN, typename OutT, int BIAS_MODE, bool RESID>
__global__ __launch_bounds__(256, 4) void gemm_tn(
    const unsigned short* __restrict__ A, const unsigned short* __restrict__ B,
    OutT* __restrict__ C, const float* __restrict__ bias,
    const float* __restrict__ resid,
    int M, int N, int K, int lda, int ldb, int ldc,
    long sA, long sB, long sC, long sR, float alpha)
{
    constexpr int BK = 64;
    constexpr int MT = TBM / 32;
    constexpr int NT = TBN / 32;
    constexpr int NAR = (TBM * BK) / (256 * 8);
    constexpr int NBR = (TBN * BK) / (256 * 8);
    __shared__ __align__(16) unsigned char smem[(TBM + TBN) * BK * 2];
    unsigned short* As = (unsigned short*)smem;
    unsigned short* Bs = (unsigned short*)(smem + TBM * BK * 2);

    const int tid  = threadIdx.x;
    const int wave = tid >> 6;
    const int lane = tid & 63;
    const int wm = (wave >> 1) * (MT * 16);
    const int wn = (wave & 1) * (NT * 16);
    const int lr = lane & 15;
    const int lq = lane >> 4;
    const int sw = lr & 7;

    const int m0 = blockIdx.y * TBM;
    const int n0 = blockIdx.x * TBN;
    A += (size_t)blockIdx.z * sA + (size_t)m0 * lda;
    B += (size_t)blockIdx.z * sB + (size_t)n0 * ldb;

    unsigned int aOff[NAR], bOff[NBR];
#pragma unroll
    for (int r = 0; r < NAR; ++r) {
        int idx = r * 256 + tid;
        int row = idx >> 3;
        int scc = (idx & 7) ^ (row & 7);
        aOff[r] = (unsigned int)(row * lda + (scc << 3)) * 2u;
    }
#pragma unroll
    for (int r = 0; r < NBR; ++r) {
        int idx = r * 256 + tid;
        int row = idx >> 3;
        int scc = (idx & 7) ^ (row & 7);
        bOff[r] = (unsigned int)(row * ldb + (scc << 3)) * 2u;
    }
    const int aBase = (wm + lr) * (BK * 2) + ((lq ^ sw) << 4);
    const int bBase = (wn + lr) * (BK * 2) + ((lq ^ sw) << 4);

    floatx4 acc[MT][NT];
#pragma unroll
    for (int i = 0; i < MT; ++i)
#pragma unroll
        for (int j = 0; j < NT; ++j) acc[i][j] = floatx4{0.f, 0.f, 0.f, 0.f};

    const char* Ab = (const char*)A;
    const char* Bb = (const char*)B;
    for (int k0 = 0; k0 < K; k0 += BK) {
#pragma unroll
        for (int r = 0; r < NAR; ++r)
            async_copy16(Ab + aOff[r], &As[(r * 256 + tid) * 8]);
#pragma unroll
        for (int r = 0; r < NBR; ++r)
            async_copy16(Bb + bOff[r], &Bs[(r * 256 + tid) * 8]);
        Ab += BK * 2;
        Bb += BK * 2;
        __syncthreads();
#pragma unroll
        for (int ks = 0; ks < BK / 32; ++ks) {
            bf16x8 af[MT], bg[NT];
#pragma unroll
            for (int i = 0; i < MT; ++i)
                af[i] = *(const bf16x8*)((const char*)As +
                        ((aBase ^ (ks << 6)) + i * (16 * BK * 2)));
#pragma unroll
            for (int j = 0; j < NT; ++j)
                bg[j] = *(const bf16x8*)((const char*)Bs +
                        ((bBase ^ (ks << 6)) + j * (16 * BK * 2)));
#pragma unroll
            for (int i = 0; i < MT; ++i)
#pragma unroll
                for (int j = 0; j < NT; ++j)
                    acc[i][j] = __builtin_amdgcn_mfma_f32_16x16x32_bf16(
                        af[i], bg[j], acc[i][j], 0, 0, 0);
        }
        __syncthreads();
    }

    // epilogue: C/D layout col=lane&15, row=(lane>>4)*4+reg
    C += (size_t)blockIdx.z * sC;
    if constexpr (RESID) resid += (size_t)blockIdx.z * sR;
    float bn[NT];
    if constexpr (BIAS_MODE == 2) {
#pragma unroll
        for (int j = 0; j < NT; ++j) bn[j] = bias[n0 + wn + j * 16 + lr];
    }
#pragma unroll
    for (int i = 0; i < MT; ++i) {
        const int mbase = m0 + wm + i * 16 + lq * 4;
        float bm4[4];
        if constexpr (BIAS_MODE == 1) {
#pragma unroll
            for (int r = 0; r < 4; ++r) bm4[r] = bias[mbase + r];
        }
#pragma unroll
        for (int j = 0; j < NT; ++j) {
            const int nn = n0 + wn + j * 16 + lr;
#pragma unroll
            for (int r = 0; r < 4; ++r) {
                float val = acc[i][j][r] * alpha;
                if constexpr (BIAS_MODE == 1) val += bm4[r];
                if constexpr (BIAS_MODE == 2) val += bn[j];
                size_t off = (size_t)(mbase + r) * ldc + nn;
                if constexpr (RESID) val += resid[off];
                if constexpr (sizeof(OutT) == 1) {
                    int pk = __builtin_amdgcn_cvt_pk_fp8_f32(val, val, 0, false);
                    C[off] = (OutT)(pk & 0xff);
                } else if constexpr (sizeof(OutT) == 2) {
                    C[off] = (OutT)f2bf(val);
                } else {
                    C[off] = val;
                }
            }
        }
    }
}

// =====================================================================
// fp8 TN GEMM (PV): C[m][n] = (sum_k A[m][k]*B[n][k]) / lsum[m], bf16 out
// =====================================================================
__global__ __launch_bounds__(256, 4) void gemm_tn_f8(
    const unsigned char* __restrict__ A, const unsigned char* __restrict__ B,
    unsigned short* __restrict__ C, const float* __restrict__ lsum,
    int M, int N, int K, int lda, int ldb, int ldc,
    long sA, long sB, long sC)
{
    constexpr int TBM = 128, TBN = 128, BKB = 128;
    __shared__ __align__(16) unsigned char As[TBM * BKB];   // 16 KB
    __shared__ __align__(16) unsigned char Bs[TBN * BKB];   // 16 KB

    const int tid  = threadIdx.x;
    const int wave = tid >> 6;
    const int lane = tid & 63;
    const int wm = (wave >> 1) * 64;
    const int wn = (wave & 1) * 64;
    const int lr = lane & 15;
    const int lq = lane >> 4;
    const int sw = lr & 7;

    const int m0 = blockIdx.y * TBM;
    const int n0 = blockIdx.x * TBN;
    A += (size_t)blockIdx.z * sA + (size_t)m0 * lda;
    B += (size_t)blockIdx.z * sB + (size_t)n0 * ldb;

    unsigned int aOff[4], bOff[4];
#pragma unroll
    for (int r = 0; r < 4; ++r) {
        int idx = r * 256 + tid;
        int row = idx >> 3;
        int scc = (idx & 7) ^ (row & 7);
        aOff[r] = (unsigned int)(row * lda + (scc << 4));
        bOff[r] = (unsigned int)(row * ldb + (scc << 4));
    }
    const int aBase = (wm + lr) * BKB + (((lq >> 1) ^ sw) << 4) + ((lq & 1) << 3);
    const int bBase = (wn + lr) * BKB + (((lq >> 1) ^ sw) << 4) + ((lq & 1) << 3);

    floatx4 acc[4][4];
#pragma unroll
    for (int i = 0; i < 4; ++i)
#pragma unroll
        for (int j = 0; j < 4; ++j) acc[i][j] = floatx4{0.f, 0.f, 0.f, 0.f};

    const char* Ab = (const char*)A;
    const char* Bb = (const char*)B;
    for (int k0 = 0; k0 < K; k0 += BKB) {
#pragma unroll
        for (int r = 0; r < 4; ++r)
            async_copy16(Ab + aOff[r], &As[(r * 256 + tid) * 16]);
#pragma unroll
        for (int r = 0; r < 4; ++r)
            async_copy16(Bb + bOff[r], &Bs[(r * 256 + tid) * 16]);
        Ab += BKB;
        Bb += BKB;
        __syncthreads();
#pragma unroll
        for (int ks = 0; ks < 4; ++ks) {             // K=32 per step
            long af[4], bg[4];
#pragma unroll
            for (int i = 0; i < 4; ++i)
                af[i] = *(const long*)((const char*)As +
                        ((aBase ^ (ks << 5)) + i * (16 * BKB)));
#pragma unroll
            for (int j = 0; j < 4; ++j)
                bg[j] = *(const long*)((const char*)Bs +
                        ((bBase ^ (ks << 5)) + j * (16 * BKB)));
#pragma unroll
            for (int i = 0; i < 4; ++i)
#pragma unroll
                for (int j = 0; j < 4; ++j)
                    acc[i][j] = __builtin_amdgcn_mfma_f32_16x16x32_fp8_fp8(
                        af[i], bg[j], acc[i][j], 0, 0, 0);
        }
        __syncthreads();
    }

    C += (size_t)blockIdx.z * sC;
    lsum += (size_t)blockIdx.z * M;
#pragma unroll
    for (int i = 0; i < 4; ++i) {
        const int mbase = m0 + wm + i * 16 + lq * 4;
        float inv4[4];
#pragma unroll
        for (int r = 0; r < 4; ++r) inv4[r] = 1.0f / lsum[mbase + r];
#pragma unroll
        for (int j = 0; j < 4; ++j) {
            const int nn = n0 + wn + j * 16 + lr;
#pragma unroll
            for (int r = 0; r < 4; ++r) {
                size_t off = (size_t)(mbase + r) * ldc + nn;
                C[off] = f2bf(acc[i][j][r] * inv4[r]);
            }
        }
    }
}

// =====================================================================
// Prep: blocks [0,1024): GN stats partials; blocks [1024,2048): weight cvt
// =====================================================================
__global__ __launch_bounds__(256) void prep(
    const float* __restrict__ net, float2* __restrict__ part,
    const float* __restrict__ wq, const float* __restrict__ wk,
    const float* __restrict__ wv, const float* __restrict__ wo,
    const float* __restrict__ bq, const float* __restrict__ bk,
    unsigned short* __restrict__ wqkb, unsigned short* __restrict__ wvb,
    unsigned short* __restrict__ wob, float* __restrict__ bqk)
{
    if (blockIdx.x < 1024) {
        const int bg = blockIdx.x >> 3, q = blockIdx.x & 7;
        const float4* p = (const float4*)(net + (size_t)bg * 65536 + q * 8192);
        float s = 0.f, ss = 0.f;
#pragma unroll
        for (int i = 0; i < 8; ++i) {
            float4 v = p[threadIdx.x + i * 256];
            s  += v.x + v.y + v.z + v.w;
            ss += v.x * v.x + v.y * v.y + v.z * v.z + v.w * v.w;
        }
#pragma unroll
        for (int o = 32; o; o >>= 1) { s += __shfl_xor(s, o); ss += __shfl_xor(ss, o); }
        __shared__ float rs[4], rss[4];
        const int wave = threadIdx.x >> 6, lane = threadIdx.x & 63;
        if (lane == 0) { rs[wave] = s; rss[wave] = ss; }
        __syncthreads();
        if (threadIdx.x == 0) {
            float2 o;
            o.x = rs[0] + rs[1] + rs[2] + rs[3];
            o.y = rss[0] + rss[1] + rss[2] + rss[3];
            part[bg * 8 + q] = o;
        }
    } else {
        const int blk = blockIdx.x - 1024;
        const int i = blk * 256 + threadIdx.x;
        wqkb[i]          = f2bf(wq[i]);
        wqkb[262144 + i] = f2bf(wk[i]);
        wvb[i] = f2bf(wv[i]);
        wob[i] = f2bf(wo[i]);
        if (i < 512) { bqk[i] = bq[i]; bqk[512 + i] = bk[i]; }
    }
}

// =====================================================================
// Normalize + transpose (+inline stats finalize):
// net[b][c][a] fp32 -> xnT[b][a][c] bf16
// =====================================================================
__global__ __launch_bounds__(256) void gn_norm_t(
    const float* __restrict__ net, const float2* __restrict__ part,
    const float* __restrict__ gamma, const float* __restrict__ beta,
    unsigned short* __restrict__ xnT)
{
    __shared__ float tile[64][65];
    const int b = blockIdx.z, c0 = blockIdx.y * 64, a0 = blockIdx.x * 64;
    const int tq = threadIdx.x >> 6;
    const int tl = threadIdx.x & 63;
    float mu4[4], rs4[4];
#pragma unroll
    for (int gg = 0; gg < 4; ++gg) {
        int g = (c0 >> 4) + gg;
        float s = 0.f, ss = 0.f;
#pragma unroll
        for (int j = 0; j < 8; ++j) {
            float2 p = part[(b * NGRP + g) * 8 + j];
            s += p.x; ss += p.y;
        }
        float mu = s * (1.f / 65536.f);
        mu4[gg] = mu;
        rs4[gg] = rsqrtf(ss * (1.f / 65536.f) - mu * mu + 1e-6f);
    }
    const float* src = net + ((size_t)b * CCH + c0) * AREA + a0;
#pragma unroll
    for (int p = 0; p < 16; ++p) {
        int cr = p * 4 + tq;
        int c  = c0 + cr;
        int gg = cr >> 4;
        float x = src[(size_t)cr * AREA + tl];
        tile[cr][tl] = (x - mu4[gg]) * rs4[gg] * gamma[c] + beta[c];
    }
    __syncthreads();
    unsigned short* dst = xnT + ((size_t)b * AREA + a0) * CCH + c0;
#pragma unroll
    for (int p = 0; p < 16; ++p) {
        int ar = p * 4 + tq;
        dst[(size_t)ar * CCH + tl] = f2bf(tile[tl][ar]);
    }
}

// =====================================================================
// Host launch
// =====================================================================
extern "C" void kernel_launch(void* const* d_in, const int* in_sizes, int n_in,
                              void* d_out, int out_size, void* d_ws, size_t ws_size,
                              hipStream_t stream)
{
    (void)in_sizes; (void)n_in; (void)out_size; (void)ws_size;
    const float* net      = (const float*)d_in[0];
    const float* gn_scale = (const float*)d_in[1];
    const float* gn_bias  = (const float*)d_in[2];
    const float* wq = (const float*)d_in[3];
    const float* bq = (const float*)d_in[4];
    const float* wk = (const float*)d_in[5];
    const float* bk = (const float*)d_in[6];
    const float* wv = (const float*)d_in[7];
    const float* bv = (const float*)d_in[8];
    const float* wo = (const float*)d_in[9];
    const float* bo = (const float*)d_in[10];
    float* out = (float*)d_out;
    char* ws = (char*)d_ws;

    // workspace layout (bytes), high-water 140 MB (< 187 MB proven):
    //   [       0,  2.0M) wqkb(1M) wvb(.5M) wob(.5M)
    //   [    2.0M,  2.2M) bqk, part, lsum
    //   [    4.0M, 20.0M) xnT [b][a][c] bf16
    //   [   20.0M, 52.0M) qkT [b][a][1024] bf16  (dead after S)
    //   [   52.0M, 60.0M) vB  [b][c][a] fp8
    //   [   60.0M, 76.0M) hT  [b][a][c] bf16
    //   [   76.0M,140.0M) Pall fp8 e4m3
    unsigned short* wqkb = (unsigned short*)(ws + 0);
    unsigned short* wvb  = (unsigned short*)(ws + 1048576);
    unsigned short* wob  = (unsigned short*)(ws + 1572864);
    float*          bqk  = (float*)(ws + 2097152);
    float2*         part = (float2*)(ws + 2105344);
    float*          lsum = (float*)(ws + 2121728);
    unsigned short* xnT  = (unsigned short*)(ws + 4194304);
    unsigned short* qkT  = (unsigned short*)(ws + 20971520);
    unsigned char*  vB   = (unsigned char*)(ws + 54525952);
    unsigned short* hT   = (unsigned short*)(ws + 62914560);
    unsigned char*  Pall = (unsigned char*)(ws + 79691776);

    const long PB  = (long)AREA * AREA;              // P bytes per batch
    const long tb  = (long)TB;
    const long qks = (long)AREA * 1024;

    hipMemsetAsync(lsum, 0, 4 * AREA * sizeof(float), stream);
    prep<<<2048, 256, 0, stream>>>(net, part, wq, wk, wv, wo, bq, bk,
                                   wqkb, wvb, wob, bqk);
    gn_norm_t<<<dim3(64, 8, 4), 256, 0, stream>>>(net, part, gn_scale, gn_bias, xnT);

    // QK fused: qkT[b][a][n] = sum_c xnT[a][c]*wqk[n][c] + bqk[n]  (N=1024)
    gemm_tn<128, 128, unsigned short, 2, false>
        <<<dim3(8, 32, 4), 256, 0, stream>>>(xnT, wqkb, qkT, bqk, nullptr,
            AREA, 1024, CCH, CCH, CCH, 1024, tb, 0, qks, 0, 1.0f);

    // S+exp 256^2 8-phase: Pall[b][i][j] = fp8(exp(s/sqrt(c) - 4)); lsum rows.
    s_exp8<<<dim3(16, 16, 4), 512, 0, stream>>>(qkT + 512, qkT, Pall, lsum);

    // V (fp8 out): vB[b][o][a] = fp8(sum_c wv[o][c]*xnT[a][c] + bv[o])
    gemm_tn<128, 128, unsigned char, 1, false>
        <<<dim3(32, 4, 4), 256, 0, stream>>>(wvb, xnT, vB, bv, nullptr,
            CCH, AREA, CCH, CCH, CCH, AREA, 0, tb, tb, 0, 1.0f);

    // PV (fp8 x fp8): hT[b][i][c] = (sum_j P_ij * v_cj) / l_i
    gemm_tn_f8<<<dim3(4, 32, 4), 256, 0, stream>>>(Pall, vB, hT, lsum,
            AREA, CCH, AREA, AREA, AREA, CCH, PB, tb, tb);

    // out[b][o][a] = net + bo[o] + sum_c wo[o][c]*hT[a][c]
    gemm_tn<128, 128, float, 1, true>
        <<<dim3(32, 4, 4), 256, 0, stream>>>(wob, hT, out, bo, net,
            CCH, AREA, CCH, CCH, CCH, AREA, 0, tb, tb, tb, 1.0f);
}